// Round 14
// baseline (188.602 us; speedup 1.0000x reference)
//
#include <hip/hip_runtime.h>
#include <hip/hip_bf16.h>

#define H_DIM 768
#define S_LEN 128
#define NT 12  // 768 / 64 K-tiles

typedef __attribute__((ext_vector_type(8))) short short8;
typedef __attribute__((ext_vector_type(4))) float f32x4;

__device__ __forceinline__ void gload_lds16(const void* g, void* l) {
  __builtin_amdgcn_global_load_lds(
      (const __attribute__((address_space(1))) unsigned int*)g,
      (__attribute__((address_space(3))) unsigned int*)l, 16, 0, 0);
}

// ---------------- Kernel 0: per-sequence mask prefix-scan + pad zeroing ----------------
__global__ __launch_bounds__(128) void prefix_kernel(
    const int* __restrict__ mask1, const int* __restrict__ mask2,
    int* __restrict__ dest, int* __restrict__ cnts,
    unsigned short* __restrict__ xc1, unsigned short* __restrict__ xc2) {
  const int sq = blockIdx.x;  // 0..127
  const int* mask = (sq < 64) ? (mask1 + sq * S_LEN) : (mask2 + (sq - 64) * S_LEN);
  unsigned short* xc = (sq < 64) ? (xc1 + (size_t)sq * S_LEN * H_DIM)
                                 : (xc2 + (size_t)(sq - 64) * S_LEN * H_DIM);
  const int tid = threadIdx.x;
  const int lane = tid & 63, wv = tid >> 6;
  const int m = mask[tid] ? 1 : 0;
  const unsigned long long bal = __ballot(m);
  const int pre = __popcll(bal & ((1ull << lane) - 1ull));
  __shared__ int wsum[2];
  if (lane == 0) wsum[wv] = __popcll(bal);
  __syncthreads();
  const int base = (wv == 1) ? wsum[0] : 0;
  const int n = wsum[0] + wsum[1];
  dest[sq * S_LEN + tid] = m ? (base + pre) : -1;
  if (tid == 0) cnts[sq] = n;
  // zero pad rows [n, ceil16(n)): staged+MFMA'd at fragment granularity, so
  // they must be zero; excluded from max/mean by real-count compares.
  const int np = (n + 15) & ~15;
  const int nz = (np - n) * 96;  // short8 chunks
  for (int c = tid; c < nz; c += 128) {
    const int row = n + c / 96;
    *reinterpret_cast<short8*>(xc + (size_t)row * H_DIM + (c % 96) * 8) =
        (short8){0, 0, 0, 0, 0, 0, 0, 0};
  }
}

// ---------------- Kernel 1: per-token L2 normalize -> COMPACTED bf16 rows ----------------
__global__ __launch_bounds__(256) void normc_kernel(
    const float* __restrict__ x1, const float* __restrict__ x2,
    const int* __restrict__ dest,
    unsigned short* __restrict__ xc1, unsigned short* __restrict__ xc2) {
  const int gid = blockIdx.x;      // 0..16383
  const int sg = gid >> 7;         // combined sequence id 0..127
  const int tok = gid & 127;
  const int d = dest[sg * S_LEN + tok];
  if (d < 0) return;               // block-uniform exit for masked tokens
  const bool is1 = (gid < 8192);
  const float* row = is1 ? (x1 + (size_t)gid * H_DIM)
                         : (x2 + (size_t)(gid - 8192) * H_DIM);
  unsigned short* orow = is1 ? (xc1 + ((size_t)(sg)*S_LEN + d) * H_DIM)
                             : (xc2 + ((size_t)(sg - 64) * S_LEN + d) * H_DIM);
  const int tid = threadIdx.x;
  float4 v = make_float4(0.f, 0.f, 0.f, 0.f);
  float ss = 0.f;
  if (tid < 192) {
    v = reinterpret_cast<const float4*>(row)[tid];
    ss = v.x * v.x + v.y * v.y + v.z * v.z + v.w * v.w;
  }
#pragma unroll
  for (int o = 32; o > 0; o >>= 1) ss += __shfl_down(ss, o);
  __shared__ float ws[4];
  if ((tid & 63) == 0) ws[tid >> 6] = ss;
  __syncthreads();
  const float scale = 1.0f / sqrtf(ws[0] + ws[1] + ws[2] + ws[3]);
  if (tid < 192) {
    union { ushort4 u; __hip_bfloat16 h[4]; } o;
    o.h[0] = __float2bfloat16(v.x * scale);
    o.h[1] = __float2bfloat16(v.y * scale);
    o.h[2] = __float2bfloat16(v.z * scale);
    o.h[3] = __float2bfloat16(v.w * scale);
    reinterpret_cast<ushort4*>(orow)[tid] = o.u;
  }
}

// ---------------- Kernel 2: one block = (a, {b0,b1}), compacted n1p x (n2p0+n2p1) ----------------
// R2's proven 8-wave 2x4 skeleton (best measured: 40% MfmaUtil, 2 blocks/CU)
// on COMPACTED panels: A staged once per K-tile, reused by both b-panels;
// fragment-granular wave-uniform guards (sequences padded to 16); index-compare
// masking. Halves the tile-step count vs R13 (2048x12 vs 4096x12).
__global__ __launch_bounds__(512, 2) void rwmd_kernel(
    const unsigned short* __restrict__ xc1, const unsigned short* __restrict__ xc2,
    const int* __restrict__ cnts, float* __restrict__ out) {
  __shared__ __align__(16) unsigned short Al[S_LEN * 64];      // 16 KB [<=128][64]
  __shared__ __align__(16) unsigned short Bl[2 * S_LEN * 64];  // 32 KB, 2 panels
  __shared__ float rpart[4][S_LEN];  // [wn][row] partial row-max
  __shared__ float cpart[2][256];    // [wm][panel*128+col] partial col-max

  // XCD-aware bijective swizzle (2048 blocks = 8 XCDs x 256): each XCD keeps
  // 8 consecutive a-panels L2-hot.
  const int bid = blockIdx.x;
  const int swz = (bid & 7) * 256 + (bid >> 3);
  const int a = swz >> 5;   // 64 a's
  const int bp = swz & 31;  // 32 b-pairs
  const int b0 = bp * 2;
  const int tid = threadIdx.x;
  const int lane = tid & 63;
  const int w = tid >> 6;
  const int wm = w >> 2, wn = w & 3;
  const int p = wn >> 1, h = wn & 1;  // panel, column-half
  const int g = lane >> 4, rl = lane & 15;

  const int n1 = cnts[a], n2_0 = cnts[64 + b0], n2_1 = cnts[64 + b0 + 1];
  const int n1p = (n1 + 15) & ~15;
  const int n2p0 = (n2_0 + 15) & ~15, n2p1 = (n2_1 + 15) & ~15;
  const int n2_p = p ? n2_1 : n2_0;    // this wave's panel real count
  const int n2p_p = p ? n2p1 : n2p0;   // padded count

  const unsigned short* A0 = xc1 + (size_t)a * (S_LEN * H_DIM);
  const unsigned short* Bp0 = xc2 + (size_t)b0 * (S_LEN * H_DIM);
  const unsigned short* Bp1 = Bp0 + (size_t)S_LEN * H_DIM;

  f32x4 acc[4][4];  // [i][j]: row wm*64+i*16+g*4+r, panel-col h*64+j*16+rl
#pragma unroll
  for (int i = 0; i < 4; ++i)
#pragma unroll
    for (int j = 0; j < 4; ++j) acc[i][j] = (f32x4){0.f, 0.f, 0.f, 0.f};

  for (int t = 0; t < NT; ++t) {
    __syncthreads();  // previous compute done before DMA overwrites LDS
    const int k0 = t * 64;
    // A: 1024 chunks (2/thread), guard row < n1p. Linear LDS dest,
    // inverse-swizzled global source chunk (rule 21).
#pragma unroll
    for (int q = 0; q < 2; ++q) {
      const int s = q * 512 + tid;
      const int row = s >> 3;
      const int cb = (s & 7) ^ (row & 7);
      if (row < n1p)
        gload_lds16(A0 + (size_t)row * H_DIM + k0 + cb * 8, Al + s * 8);
    }
    // B: 2048 chunks (4/thread); q<2 -> panel 0, q>=2 -> panel 1 (compile-time)
#pragma unroll
    for (int q = 0; q < 4; ++q) {
      const int s = q * 512 + tid;
      const int prow = (s >> 3) & 127;
      const int cb = (s & 7) ^ (prow & 7);
      const unsigned short* Bsrc = (q < 2) ? Bp0 : Bp1;
      const int np = (q < 2) ? n2p0 : n2p1;
      if (prow < np)
        gload_lds16(Bsrc + (size_t)prow * H_DIM + k0 + cb * 8, Bl + s * 8);
    }
    __syncthreads();  // drains vmcnt(0)
#pragma unroll
    for (int kf = 0; kf < 2; ++kf) {
      const int slot = (kf * 4 + g) ^ (rl & 7);  // frag row&7 == rl&7
      short8 av[4], bv[4];
#pragma unroll
      for (int i = 0; i < 4; ++i)
        if (wm * 64 + i * 16 < n1p)  // wave-uniform
          av[i] = *reinterpret_cast<const short8*>(
              &Al[(wm * 64 + i * 16 + rl) * 64 + slot * 8]);
#pragma unroll
      for (int j = 0; j < 4; ++j)
        if (h * 64 + j * 16 < n2p_p)  // wave-uniform
          bv[j] = *reinterpret_cast<const short8*>(
              &Bl[p * 8192 + (h * 64 + j * 16 + rl) * 64 + slot * 8]);
      __builtin_amdgcn_s_setprio(1);
#pragma unroll
      for (int i = 0; i < 4; ++i)
#pragma unroll
        for (int j = 0; j < 4; ++j)
          if (wm * 64 + i * 16 < n1p && h * 64 + j * 16 < n2p_p)
            acc[i][j] = __builtin_amdgcn_mfma_f32_16x16x32_bf16(
                av[i], bv[j], acc[i][j], 0, 0, 0);
      __builtin_amdgcn_s_setprio(0);
    }
  }

  // ---- in-register masked reductions (index-compare masking) ----
#pragma unroll
  for (int i = 0; i < 4; ++i) {
#pragma unroll
    for (int r = 0; r < 4; ++r) {
      float pm = -INFINITY;  // stays -inf for waves with no active cols
#pragma unroll
      for (int j = 0; j < 4; ++j) {
        const int col = h * 64 + j * 16 + rl;  // within panel
        pm = fmaxf(pm, (col < n2_p) ? acc[i][j][r] : -INFINITY);
      }
#pragma unroll
      for (int o = 1; o < 16; o <<= 1) pm = fmaxf(pm, __shfl_xor(pm, o));
      if (rl == 0) rpart[wn][wm * 64 + i * 16 + g * 4 + r] = pm;
    }
  }
#pragma unroll
  for (int j = 0; j < 4; ++j) {
    float cm = -INFINITY;
#pragma unroll
    for (int i = 0; i < 4; ++i)
#pragma unroll
      for (int r = 0; r < 4; ++r) {
        const int row = wm * 64 + i * 16 + g * 4 + r;
        cm = fmaxf(cm, (row < n1) ? acc[i][j][r] : -INFINITY);  // excl. pad rows
      }
    cm = fmaxf(cm, __shfl_xor(cm, 16));
    cm = fmaxf(cm, __shfl_xor(cm, 32));
    if (g == 0) cpart[wm][p * 128 + h * 64 + j * 16 + rl] = cm;
  }
  __syncthreads();

  // ---- final masked means: wave 0 -> pair b0, wave 1 -> pair b1 ----
  if (w < 2) {
    const int n2w = w ? n2_1 : n2_0;
    float v1 = 0.f, v2 = 0.f;
#pragma unroll
    for (int q = 0; q < 2; ++q) {
      const int r = lane + q * 64;
      if (r < n1) v1 += fmaxf(rpart[2 * w][r], rpart[2 * w + 1][r]);
      if (r < n2w) v2 += fmaxf(cpart[0][w * 128 + r], cpart[1][w * 128 + r]);
    }
#pragma unroll
    for (int o = 32; o > 0; o >>= 1) {
      v1 += __shfl_down(v1, o);
      v2 += __shfl_down(v2, o);
    }
    if (lane == 0)
      out[a * 64 + b0 + w] = 0.5f * (v1 / (float)n1 + v2 / (float)n2w);
  }
}

extern "C" void kernel_launch(void* const* d_in, const int* in_sizes, int n_in,
                              void* d_out, int out_size, void* d_ws, size_t ws_size,
                              hipStream_t stream) {
  const float* x1 = (const float*)d_in[0];
  const int* mask1 = (const int*)d_in[1];
  const float* x2 = (const float*)d_in[2];
  const int* mask2 = (const int*)d_in[3];
  float* out = (float*)d_out;

  unsigned short* xc1 = (unsigned short*)d_ws;               // 12.58 MB compacted A
  unsigned short* xc2 = xc1 + (size_t)64 * S_LEN * H_DIM;    // 12.58 MB compacted B
  int* dest = (int*)(xc2 + (size_t)64 * S_LEN * H_DIM);      // 128*128 ints
  int* cnts = dest + 128 * S_LEN;                            // 128 ints

  prefix_kernel<<<128, 128, 0, stream>>>(mask1, mask2, dest, cnts, xc1, xc2);
  normc_kernel<<<16384, 256, 0, stream>>>(x1, x2, dest, xc1, xc2);
  rwmd_kernel<<<64 * 32, 512, 0, stream>>>(xc1, xc2, cnts, out);
}

// Round 15
// 141.946 us; speedup vs baseline: 1.3287x; 1.3287x over previous
//
#include <hip/hip_runtime.h>
#include <hip/hip_bf16.h>

#define H_DIM 768
#define S_LEN 128
#define NT6 6  // 768 / 128 K-tiles

typedef __attribute__((ext_vector_type(8))) short short8;
typedef __attribute__((ext_vector_type(4))) float f32x4;

__device__ __forceinline__ void gload_lds16(const void* g, void* l) {
  __builtin_amdgcn_global_load_lds(
      (const __attribute__((address_space(1))) unsigned int*)g,
      (__attribute__((address_space(3))) unsigned int*)l, 16, 0, 0);
}

// ---------------- Kernel 0: per-sequence mask prefix-scan + pad zeroing ----------------
__global__ __launch_bounds__(128) void prefix_kernel(
    const int* __restrict__ mask1, const int* __restrict__ mask2,
    int* __restrict__ dest, int* __restrict__ cnts,
    unsigned short* __restrict__ xc1, unsigned short* __restrict__ xc2) {
  const int sq = blockIdx.x;  // 0..127
  const int* mask = (sq < 64) ? (mask1 + sq * S_LEN) : (mask2 + (sq - 64) * S_LEN);
  unsigned short* xc = (sq < 64) ? (xc1 + (size_t)sq * S_LEN * H_DIM)
                                 : (xc2 + (size_t)(sq - 64) * S_LEN * H_DIM);
  const int tid = threadIdx.x;
  const int lane = tid & 63, wv = tid >> 6;
  const int m = mask[tid] ? 1 : 0;
  const unsigned long long bal = __ballot(m);
  const int pre = __popcll(bal & ((1ull << lane) - 1ull));
  __shared__ int wsum[2];
  if (lane == 0) wsum[wv] = __popcll(bal);
  __syncthreads();
  const int base = (wv == 1) ? wsum[0] : 0;
  const int n = wsum[0] + wsum[1];
  dest[sq * S_LEN + tid] = m ? (base + pre) : -1;
  if (tid == 0) cnts[sq] = n;
  // zero pad rows [n, ceil16(n)): staged+MFMA'd at fragment granularity, so
  // they must be zero; excluded from max/mean by real-count compares.
  const int np = (n + 15) & ~15;
  const int nz = (np - n) * 96;  // short8 chunks
  for (int c = tid; c < nz; c += 128) {
    const int row = n + c / 96;
    *reinterpret_cast<short8*>(xc + (size_t)row * H_DIM + (c % 96) * 8) =
        (short8){0, 0, 0, 0, 0, 0, 0, 0};
  }
}

// ---------------- Kernel 1: per-token L2 normalize -> COMPACTED bf16 rows ----------------
__global__ __launch_bounds__(256) void normc_kernel(
    const float* __restrict__ x1, const float* __restrict__ x2,
    const int* __restrict__ dest,
    unsigned short* __restrict__ xc1, unsigned short* __restrict__ xc2) {
  const int gid = blockIdx.x;      // 0..16383
  const int sg = gid >> 7;         // combined sequence id 0..127
  const int tok = gid & 127;
  const int d = dest[sg * S_LEN + tok];
  if (d < 0) return;               // block-uniform exit for masked tokens
  const bool is1 = (gid < 8192);
  const float* row = is1 ? (x1 + (size_t)gid * H_DIM)
                         : (x2 + (size_t)(gid - 8192) * H_DIM);
  unsigned short* orow = is1 ? (xc1 + ((size_t)(sg)*S_LEN + d) * H_DIM)
                             : (xc2 + ((size_t)(sg - 64) * S_LEN + d) * H_DIM);
  const int tid = threadIdx.x;
  float4 v = make_float4(0.f, 0.f, 0.f, 0.f);
  float ss = 0.f;
  if (tid < 192) {
    v = reinterpret_cast<const float4*>(row)[tid];
    ss = v.x * v.x + v.y * v.y + v.z * v.z + v.w * v.w;
  }
#pragma unroll
  for (int o = 32; o > 0; o >>= 1) ss += __shfl_down(ss, o);
  __shared__ float ws[4];
  if ((tid & 63) == 0) ws[tid >> 6] = ss;
  __syncthreads();
  const float scale = 1.0f / sqrtf(ws[0] + ws[1] + ws[2] + ws[3]);
  if (tid < 192) {
    union { ushort4 u; __hip_bfloat16 h[4]; } o;
    o.h[0] = __float2bfloat16(v.x * scale);
    o.h[1] = __float2bfloat16(v.y * scale);
    o.h[2] = __float2bfloat16(v.z * scale);
    o.h[3] = __float2bfloat16(v.w * scale);
    reinterpret_cast<ushort4*>(orow)[tid] = o.u;
  }
}

// ---------------- Kernel 2: one block = one (a,b) pair, BK=128, 6 drain-steps ----------------
// R13's proven compacted skeleton with HALF the barrier-drain steps: BK=128,
// 512 threads / 8 waves (2x4), wave tile 64x32 (acc[4][2] = 32 AGPR).
// LDS 64 KB (A + B single-buffered) -> 2 blocks/CU (16 waves). No XCD swizzle
// (R14: it thrashed L2, FETCH 31->225 MB). Index-compare masking; guards are
// wave-uniform at fragment granularity; pad rows are zeroed by prefix_kernel.
__global__ __launch_bounds__(512, 4) void rwmd_kernel(
    const unsigned short* __restrict__ xc1, const unsigned short* __restrict__ xc2,
    const int* __restrict__ cnts, float* __restrict__ out) {
  __shared__ __align__(16) unsigned char smem[65536];      // 64 KB
  unsigned short* const Al = (unsigned short*)smem;        // [<=128][128] bf16, 32 KB
  unsigned short* const Bl = (unsigned short*)(smem + 32768);
  float* const rpart = (float*)smem;                       // overlay: [4][128]
  float* const cpart = (float*)(smem + 2048);              // overlay: [2][128]

  const int a = blockIdx.x >> 6;
  const int b = blockIdx.x & 63;
  const int n1 = cnts[a], n2 = cnts[64 + b];
  const int n1p = (n1 + 15) & ~15, n2p = (n2 + 15) & ~15;
  const int tid = threadIdx.x;
  const int lane = tid & 63;
  const int w = tid >> 6;
  const int wm = w >> 2, wn = w & 3;
  const int g = lane >> 4, rl = lane & 15;

  const unsigned short* A0 = xc1 + (size_t)a * (S_LEN * H_DIM);
  const unsigned short* B0 = xc2 + (size_t)b * (S_LEN * H_DIM);

  f32x4 acc[4][2];  // row = wm*64 + i*16 + g*4 + r, col = wn*32 + j*16 + rl
#pragma unroll
  for (int i = 0; i < 4; ++i)
#pragma unroll
    for (int j = 0; j < 2; ++j) acc[i][j] = (f32x4){0.f, 0.f, 0.f, 0.f};

  for (int t = 0; t < NT6; ++t) {
    __syncthreads();  // previous compute done before DMA overwrites LDS
    const int k0 = t * 128;
    // 16 chunks (16B) per 128-elem row; 2048 chunks per operand; 4+4/thread.
    // Linear LDS dest, inverse-swizzled global source chunk (rule 21;
    // involution c ^ (row&15)). Guards skip pad-space rows.
#pragma unroll
    for (int q = 0; q < 4; ++q) {
      const int s = q * 512 + tid;
      const int row = s >> 4;
      const int cb = (s & 15) ^ (row & 15);
      const size_t src = (size_t)row * H_DIM + k0 + cb * 8;
      if (row < n1p) gload_lds16(A0 + src, Al + s * 8);
      if (row < n2p) gload_lds16(B0 + src, Bl + s * 8);
    }
    __syncthreads();  // drains vmcnt(0)
#pragma unroll
    for (int kf = 0; kf < 4; ++kf) {
      const int slot = (kf * 4 + g) ^ rl;  // frag row&15 == rl
      short8 av[4], bv[2];
#pragma unroll
      for (int i = 0; i < 4; ++i)
        if (wm * 64 + i * 16 < n1p)  // wave-uniform
          av[i] = *reinterpret_cast<const short8*>(
              &Al[(wm * 64 + i * 16 + rl) * 128 + slot * 8]);
#pragma unroll
      for (int j = 0; j < 2; ++j)
        if (wn * 32 + j * 16 < n2p)  // wave-uniform
          bv[j] = *reinterpret_cast<const short8*>(
              &Bl[(wn * 32 + j * 16 + rl) * 128 + slot * 8]);
      __builtin_amdgcn_s_setprio(1);
#pragma unroll
      for (int i = 0; i < 4; ++i)
#pragma unroll
        for (int j = 0; j < 2; ++j)
          if (wm * 64 + i * 16 < n1p && wn * 32 + j * 16 < n2p)
            acc[i][j] = __builtin_amdgcn_mfma_f32_16x16x32_bf16(
                av[i], bv[j], acc[i][j], 0, 0, 0);
      __builtin_amdgcn_s_setprio(0);
    }
  }

  __syncthreads();  // all LDS reads retired -> safe to overlay rpart/cpart

  // ---- in-register masked reductions (index-compare masking) ----
#pragma unroll
  for (int i = 0; i < 4; ++i) {
#pragma unroll
    for (int r = 0; r < 4; ++r) {
      float pm = -INFINITY;  // stays -inf for waves with no valid cols/rows
#pragma unroll
      for (int j = 0; j < 2; ++j) {
        const int col = wn * 32 + j * 16 + rl;
        pm = fmaxf(pm, (col < n2) ? acc[i][j][r] : -INFINITY);
      }
#pragma unroll
      for (int o = 1; o < 16; o <<= 1) pm = fmaxf(pm, __shfl_xor(pm, o));
      if (rl == 0) rpart[wn * S_LEN + wm * 64 + i * 16 + g * 4 + r] = pm;
    }
  }
#pragma unroll
  for (int j = 0; j < 2; ++j) {
    float cm = -INFINITY;
#pragma unroll
    for (int i = 0; i < 4; ++i)
#pragma unroll
      for (int r = 0; r < 4; ++r) {
        const int row = wm * 64 + i * 16 + g * 4 + r;
        cm = fmaxf(cm, (row < n1) ? acc[i][j][r] : -INFINITY);
      }
    cm = fmaxf(cm, __shfl_xor(cm, 16));
    cm = fmaxf(cm, __shfl_xor(cm, 32));
    if (g == 0) cpart[wm * S_LEN + wn * 32 + j * 16 + rl] = cm;
  }
  __syncthreads();

  // ---- final masked means on wave 0 (denominators = real counts) ----
  if (w == 0) {
    float v1 = 0.f, v2 = 0.f;
#pragma unroll
    for (int q = 0; q < 2; ++q) {
      const int r = lane + q * 64;
      if (r < n1)
        v1 += fmaxf(fmaxf(rpart[r], rpart[S_LEN + r]),
                    fmaxf(rpart[2 * S_LEN + r], rpart[3 * S_LEN + r]));
      if (r < n2) v2 += fmaxf(cpart[r], cpart[S_LEN + r]);
    }
#pragma unroll
    for (int o = 32; o > 0; o >>= 1) {
      v1 += __shfl_down(v1, o);
      v2 += __shfl_down(v2, o);
    }
    if (lane == 0) out[a * 64 + b] = 0.5f * (v1 / (float)n1 + v2 / (float)n2);
  }
}

extern "C" void kernel_launch(void* const* d_in, const int* in_sizes, int n_in,
                              void* d_out, int out_size, void* d_ws, size_t ws_size,
                              hipStream_t stream) {
  const float* x1 = (const float*)d_in[0];
  const int* mask1 = (const int*)d_in[1];
  const float* x2 = (const float*)d_in[2];
  const int* mask2 = (const int*)d_in[3];
  float* out = (float*)d_out;

  unsigned short* xc1 = (unsigned short*)d_ws;               // 12.58 MB compacted A
  unsigned short* xc2 = xc1 + (size_t)64 * S_LEN * H_DIM;    // 12.58 MB compacted B
  int* dest = (int*)(xc2 + (size_t)64 * S_LEN * H_DIM);      // 128*128 ints
  int* cnts = dest + 128 * S_LEN;                            // 128 ints

  prefix_kernel<<<128, 128, 0, stream>>>(mask1, mask2, dest, cnts, xc1, xc2);
  normc_kernel<<<16384, 256, 0, stream>>>(x1, x2, dest, xc1, xc2);
  rwmd_kernel<<<64 * 64, 512, 0, stream>>>(xc1, xc2, cnts, out);
}

// Round 16
// 122.001 us; speedup vs baseline: 1.5459x; 1.1635x over previous
//
#include <hip/hip_runtime.h>
#include <hip/hip_bf16.h>

#define H_DIM 768
#define S_LEN 128
#define NT 12  // 768 / 64 K-tiles

typedef __attribute__((ext_vector_type(8))) short short8;
typedef __attribute__((ext_vector_type(4))) float f32x4;

__device__ __forceinline__ void gload_lds16(const void* g, void* l) {
  __builtin_amdgcn_global_load_lds(
      (const __attribute__((address_space(1))) unsigned int*)g,
      (__attribute__((address_space(3))) unsigned int*)l, 16, 0, 0);
}

// ---------------- Kernel 0: prep — prefix scans + pad zeroing ----------------
// Blocks 0..63: x1 sequence sq (128 tokens) -> dest1, cnts1, zero pad rows of xc1[sq].
// Blocks 64..95: x2 PAIR pp (256 tokens of b0|b1 concatenated) -> dest2 (pair-
// local compacted index), cnts2 (total), nsplit2 (b0's count), zero pad rows.
__global__ __launch_bounds__(256) void prep_kernel(
    const int* __restrict__ mask1, const int* __restrict__ mask2,
    int* __restrict__ dest1, int* __restrict__ dest2,
    int* __restrict__ cnts1, int* __restrict__ cnts2, int* __restrict__ nsplit2,
    unsigned short* __restrict__ xc1, unsigned short* __restrict__ xc2p) {
  const int blk = blockIdx.x;
  const int tid = threadIdx.x;
  const int lane = tid & 63, wv = tid >> 6;
  __shared__ int wsum[4];
  if (blk < 64) {  // x1 sequence
    const int sq = blk;
    int n;
    if (tid < 128) {
      const int m = mask1[sq * S_LEN + tid] ? 1 : 0;
      const unsigned long long bal = __ballot(m);
      const int pre = __popcll(bal & ((1ull << lane) - 1ull));
      if (lane == 0) wsum[wv] = __popcll(bal);
      __syncthreads();
      const int base = (wv == 1) ? wsum[0] : 0;
      n = wsum[0] + wsum[1];
      dest1[sq * S_LEN + tid] = m ? (base + pre) : -1;
      if (tid == 0) cnts1[sq] = n;
    } else {
      __syncthreads();
      n = wsum[0] + wsum[1];
    }
    const int np = (n + 15) & ~15;
    unsigned short* xc = xc1 + (size_t)sq * S_LEN * H_DIM;
    const int nz = (np - n) * 96;  // short8 chunks in pad rows
    for (int c = tid; c < nz; c += 256) {
      const int row = n + c / 96;
      *reinterpret_cast<short8*>(xc + (size_t)row * H_DIM + (c % 96) * 8) =
          (short8){0, 0, 0, 0, 0, 0, 0, 0};
    }
  } else {  // x2 pair (256 tokens)
    const int pp = blk - 64;
    const int m = mask2[pp * 256 + tid] ? 1 : 0;
    const unsigned long long bal = __ballot(m);
    const int pre = __popcll(bal & ((1ull << lane) - 1ull));
    if (lane == 0) wsum[wv] = __popcll(bal);
    __syncthreads();
    int base = 0;
#pragma unroll
    for (int q = 0; q < 4; ++q)
      if (q < wv) base += wsum[q];
    const int n = wsum[0] + wsum[1] + wsum[2] + wsum[3];
    dest2[pp * 256 + tid] = m ? (base + pre) : -1;
    if (tid == 0) {
      cnts2[pp] = n;
      nsplit2[pp] = wsum[0] + wsum[1];  // count of first 128 tokens (= b0's n)
    }
    const int np = (n + 15) & ~15;
    unsigned short* xc = xc2p + (size_t)pp * 256 * H_DIM;
    const int nz = (np - n) * 96;
    for (int c = tid; c < nz; c += 256) {
      const int row = n + c / 96;
      *reinterpret_cast<short8*>(xc + (size_t)row * H_DIM + (c % 96) * 8) =
          (short8){0, 0, 0, 0, 0, 0, 0, 0};
    }
  }
}

// ---------------- Kernel 1: per-token L2 normalize -> compacted bf16 rows ----------------
__global__ __launch_bounds__(256) void normc_kernel(
    const float* __restrict__ x1, const float* __restrict__ x2,
    const int* __restrict__ dest1, const int* __restrict__ dest2,
    unsigned short* __restrict__ xc1, unsigned short* __restrict__ xc2p) {
  const int gid = blockIdx.x;  // 0..16383
  const bool is1 = (gid < 8192);
  int d;
  const float* row;
  unsigned short* orow;
  if (is1) {
    const int sq = gid >> 7, tok = gid & 127;
    d = dest1[sq * S_LEN + tok];
    row = x1 + (size_t)gid * H_DIM;
    orow = xc1 + ((size_t)sq * S_LEN + d) * H_DIM;
  } else {
    const int t2 = gid - 8192;
    const int pp = t2 >> 8, tokp = t2 & 255;
    d = dest2[pp * 256 + tokp];
    row = x2 + (size_t)t2 * H_DIM;
    orow = xc2p + ((size_t)pp * 256 + d) * H_DIM;
  }
  if (d < 0) return;  // block-uniform exit for masked tokens
  const int tid = threadIdx.x;
  float4 v = make_float4(0.f, 0.f, 0.f, 0.f);
  float ss = 0.f;
  if (tid < 192) {
    v = reinterpret_cast<const float4*>(row)[tid];
    ss = v.x * v.x + v.y * v.y + v.z * v.z + v.w * v.w;
  }
#pragma unroll
  for (int o = 32; o > 0; o >>= 1) ss += __shfl_down(ss, o);
  __shared__ float ws[4];
  if ((tid & 63) == 0) ws[tid >> 6] = ss;
  __syncthreads();
  const float scale = 1.0f / sqrtf(ws[0] + ws[1] + ws[2] + ws[3]);
  if (tid < 192) {
    union { ushort4 u; __hip_bfloat16 h[4]; } o;
    o.h[0] = __float2bfloat16(v.x * scale);
    o.h[1] = __float2bfloat16(v.y * scale);
    o.h[2] = __float2bfloat16(v.z * scale);
    o.h[3] = __float2bfloat16(v.w * scale);
    reinterpret_cast<ushort4*>(orow)[tid] = o.u;
  }
}

// ---------------- Kernel 2: one block = (a, b-pair), compacted 128 x n2cat tile ----------------
// Concatenated-B: the pair's two sequences live in ONE compacted panel of
// n2cat rows, so the K-loop is exactly the R13/R10 proven shape (one A panel,
// one B panel, two row guards) at HALF the block-step count. The b0/b1 split
// happens only in the epilogue via the nsplit boundary (wave-uniform).
// Staged-bytes law (fits R2/R10/R13 within 3%): wall ~ staged_bytes/17B/cyc/CU;
// this cuts staged bytes ~35% vs R13.
__global__ __launch_bounds__(512, 4) void rwmd_kernel(
    const unsigned short* __restrict__ xc1, const unsigned short* __restrict__ xc2p,
    const int* __restrict__ cnts1, const int* __restrict__ cnts2,
    const int* __restrict__ nsplit2, float* __restrict__ out) {
  __shared__ __align__(16) unsigned char smem[49152];          // 48 KB
  unsigned short* const Al = (unsigned short*)smem;            // [<=128][64], 16 KB
  unsigned short* const Bl = (unsigned short*)(smem + 16384);  // [<=256][64], 32 KB
  float* const rpart0 = (float*)smem;                          // overlay [4][128]
  float* const rpart1 = (float*)(smem + 2048);                 // overlay [4][128]
  float* const cpart = (float*)(smem + 4096);                  // overlay [2][256]

  const int a = blockIdx.x >> 5;   // 64 a's
  const int bp = blockIdx.x & 31;  // 32 b-pairs
  const int n1 = cnts1[a], n2 = cnts2[bp];
  const int n1p = (n1 + 15) & ~15, n2p = (n2 + 15) & ~15;
  const int tid = threadIdx.x;
  const int lane = tid & 63;
  const int w = tid >> 6;
  const int wm = w >> 2, wn = w & 3;
  const int g = lane >> 4, rl = lane & 15;

  const unsigned short* A0 = xc1 + (size_t)a * (S_LEN * H_DIM);
  const unsigned short* B0 = xc2p + (size_t)bp * (256 * H_DIM);

  f32x4 acc[4][4];  // row = wm*64+i*16+g*4+r, col = wn*64+j*16+rl
#pragma unroll
  for (int i = 0; i < 4; ++i)
#pragma unroll
    for (int j = 0; j < 4; ++j) acc[i][j] = (f32x4){0.f, 0.f, 0.f, 0.f};

  for (int t = 0; t < NT; ++t) {
    __syncthreads();  // previous compute done before DMA overwrites LDS
    const int k0 = t * 64;
    // A: 1024 chunks (2/thread); B: 2048 chunks (4/thread). Linear LDS dest,
    // inverse-swizzled global source chunk (rule 21). Row guards skip pad space.
#pragma unroll
    for (int q = 0; q < 2; ++q) {
      const int s = q * 512 + tid;
      const int row = s >> 3;
      const int cb = (s & 7) ^ (row & 7);
      if (row < n1p)
        gload_lds16(A0 + (size_t)row * H_DIM + k0 + cb * 8, Al + s * 8);
    }
#pragma unroll
    for (int q = 0; q < 4; ++q) {
      const int s = q * 512 + tid;
      const int row = s >> 3;  // 0..255
      const int cb = (s & 7) ^ (row & 7);
      if (row < n2p)
        gload_lds16(B0 + (size_t)row * H_DIM + k0 + cb * 8, Bl + s * 8);
    }
    __syncthreads();  // drains vmcnt(0)
#pragma unroll
    for (int kf = 0; kf < 2; ++kf) {
      const int slot = (kf * 4 + g) ^ (rl & 7);  // frag row&7 == rl&7
      short8 av[4], bv[4];
#pragma unroll
      for (int i = 0; i < 4; ++i)
        if (wm * 64 + i * 16 < n1p)  // wave-uniform
          av[i] = *reinterpret_cast<const short8*>(
              &Al[(wm * 64 + i * 16 + rl) * 64 + slot * 8]);
#pragma unroll
      for (int j = 0; j < 4; ++j)
        if (wn * 64 + j * 16 < n2p)  // wave-uniform
          bv[j] = *reinterpret_cast<const short8*>(
              &Bl[(wn * 64 + j * 16 + rl) * 64 + slot * 8]);
      __builtin_amdgcn_s_setprio(1);
#pragma unroll
      for (int i = 0; i < 4; ++i)
#pragma unroll
        for (int j = 0; j < 4; ++j)
          if (wm * 64 + i * 16 < n1p && wn * 64 + j * 16 < n2p)
            acc[i][j] = __builtin_amdgcn_mfma_f32_16x16x32_bf16(
                av[i], bv[j], acc[i][j], 0, 0, 0);
      __builtin_amdgcn_s_setprio(0);
    }
  }

  const int nsplit = nsplit2[bp];  // b0's real count (epilogue-only load)
  __syncthreads();                 // staging LDS dead -> safe to overlay

  // ---- split row-maxes (per-b) + col-maxes, in registers ----
#pragma unroll
  for (int i = 0; i < 4; ++i) {
#pragma unroll
    for (int r = 0; r < 4; ++r) {
      float pm0 = -INFINITY, pm1 = -INFINITY;
#pragma unroll
      for (int j = 0; j < 4; ++j) {
        const int col = wn * 64 + j * 16 + rl;
        const float v = acc[i][j][r];
        pm0 = fmaxf(pm0, (col < nsplit) ? v : -INFINITY);
        pm1 = fmaxf(pm1, (col >= nsplit && col < n2) ? v : -INFINITY);
      }
#pragma unroll
      for (int o = 1; o < 16; o <<= 1) {
        pm0 = fmaxf(pm0, __shfl_xor(pm0, o));
        pm1 = fmaxf(pm1, __shfl_xor(pm1, o));
      }
      if (rl == 0) {
        const int row = wm * 64 + i * 16 + g * 4 + r;
        rpart0[wn * S_LEN + row] = pm0;
        rpart1[wn * S_LEN + row] = pm1;
      }
    }
  }
#pragma unroll
  for (int j = 0; j < 4; ++j) {
    float cm = -INFINITY;
#pragma unroll
    for (int i = 0; i < 4; ++i)
#pragma unroll
      for (int r = 0; r < 4; ++r) {
        const int row = wm * 64 + i * 16 + g * 4 + r;
        cm = fmaxf(cm, (row < n1) ? acc[i][j][r] : -INFINITY);
      }
    cm = fmaxf(cm, __shfl_xor(cm, 16));
    cm = fmaxf(cm, __shfl_xor(cm, 32));
    if (g == 0) cpart[wm * 256 + wn * 64 + j * 16 + rl] = cm;
  }
  __syncthreads();

  // ---- final means: wave 0 -> b0 (cols [0,nsplit)), wave 1 -> b1 ([nsplit,n2)) ----
  if (w < 2) {
    const float* rp = w ? rpart1 : rpart0;
    const int clo = w ? nsplit : 0;
    const int chi = w ? n2 : nsplit;
    float v1 = 0.f, v2 = 0.f;
#pragma unroll
    for (int q = 0; q < 2; ++q) {
      const int r = lane + q * 64;
      if (r < n1)
        v1 += fmaxf(fmaxf(rp[r], rp[S_LEN + r]),
                    fmaxf(rp[2 * S_LEN + r], rp[3 * S_LEN + r]));
    }
#pragma unroll
    for (int q = 0; q < 4; ++q) {
      const int c = lane + q * 64;
      if (c >= clo && c < chi) v2 += fmaxf(cpart[c], cpart[256 + c]);
    }
#pragma unroll
    for (int o = 32; o > 0; o >>= 1) {
      v1 += __shfl_down(v1, o);
      v2 += __shfl_down(v2, o);
    }
    if (lane == 0)
      out[a * 64 + bp * 2 + w] =
          0.5f * (v1 / (float)n1 + v2 / (float)(chi - clo));
  }
}

extern "C" void kernel_launch(void* const* d_in, const int* in_sizes, int n_in,
                              void* d_out, int out_size, void* d_ws, size_t ws_size,
                              hipStream_t stream) {
  const float* x1 = (const float*)d_in[0];
  const int* mask1 = (const int*)d_in[1];
  const float* x2 = (const float*)d_in[2];
  const int* mask2 = (const int*)d_in[3];
  float* out = (float*)d_out;

  unsigned short* xc1 = (unsigned short*)d_ws;                 // 12.58 MB compacted A
  unsigned short* xc2p = xc1 + (size_t)64 * S_LEN * H_DIM;     // 12.58 MB pair-concat B
  int* dest1 = (int*)(xc2p + (size_t)32 * 256 * H_DIM);        // 64*128
  int* dest2 = dest1 + 64 * S_LEN;                             // 32*256
  int* cnts1 = dest2 + 32 * 256;                               // 64
  int* cnts2 = cnts1 + 64;                                     // 32
  int* nsplit2 = cnts2 + 32;                                   // 32

  prep_kernel<<<96, 256, 0, stream>>>(mask1, mask2, dest1, dest2, cnts1, cnts2,
                                      nsplit2, xc1, xc2p);
  normc_kernel<<<16384, 256, 0, stream>>>(x1, x2, dest1, dest2, xc1, xc2p);
  rwmd_kernel<<<64 * 32, 512, 0, stream>>>(xc1, xc2p, cnts1, cnts2, nsplit2, out);
}